// Round 1
// baseline (830.651 us; speedup 1.0000x reference)
//
#include <hip/hip_runtime.h>
#include <hip/hip_bf16.h>

// GCN: 3x GCNConv (11->32->64->128) + mean-pool + MLP (128->64->12)
// N=50000 nodes, E=600000 edges, G=512 graphs.

#define F_IN 11
#define GG 512
#define TGT 12

// ---------------- degree + normalization ----------------

__global__ void deg_kernel(const int* __restrict__ dst, float* __restrict__ deg, int E) {
    int i = blockIdx.x * blockDim.x + threadIdx.x;
    if (i < E) atomicAdd(&deg[dst[i]], 1.0f);
}

__global__ void dis_kernel(float* __restrict__ deg_to_dis, int n) {
    int i = blockIdx.x * blockDim.x + threadIdx.x;
    if (i < n) deg_to_dis[i] = rsqrtf(1.0f + deg_to_dis[i]);
}

__global__ void edge_norm_kernel(const int* __restrict__ src, const int* __restrict__ dst,
                                 const float* __restrict__ dis, float* __restrict__ enorm, int E) {
    int i = blockIdx.x * blockDim.x + threadIdx.x;
    if (i < E) enorm[i] = dis[src[i]] * dis[dst[i]];
}

// ---------------- dense GEMM: hw = h @ W  (W: FI x FO, row-major) ----------------

template <int FI, int FO>
__global__ void gemm_kernel(const float* __restrict__ h, const float* __restrict__ W,
                            float* __restrict__ hw, int n) {
    __shared__ float sW[FI * FO];
    for (int i = threadIdx.x; i < FI * FO; i += blockDim.x) sW[i] = W[i];
    __syncthreads();
    constexpr int NPB = 256 / FO;  // nodes per block
    int node = blockIdx.x * NPB + (int)(threadIdx.x / FO);
    int fo = threadIdx.x % FO;
    if (node < n) {
        const float* row = h + (size_t)node * FI;
        float acc = 0.0f;
#pragma unroll
        for (int fi = 0; fi < FI; ++fi) acc += row[fi] * sW[fi * FO + fo];
        hw[(size_t)node * FO + fo] = acc;
    }
}

// ---------------- edge scatter: agg[dst] += hw[src] * enorm ----------------

template <int FO>
__global__ void scatter_kernel(const int* __restrict__ src, const int* __restrict__ dst,
                               const float* __restrict__ enorm, const float* __restrict__ hw,
                               float* __restrict__ agg, int E) {
    long long idx = (long long)blockIdx.x * blockDim.x + threadIdx.x;
    int e = (int)(idx / FO);
    int f = (int)(idx % FO);
    if (e < E) {
        int s = src[e], d = dst[e];
        float v = hw[(size_t)s * FO + f] * enorm[e];
        atomicAdd(&agg[(size_t)d * FO + f], v);
    }
}

// ---------------- finalize: h = [relu](agg + hw*dis^2 + b), in-place into agg ----------------

template <int FO, bool RELU>
__global__ void finalize_kernel(const float* __restrict__ hw, const float* __restrict__ dis,
                                const float* __restrict__ b, float* __restrict__ agg, int n) {
    long long idx = (long long)blockIdx.x * blockDim.x + threadIdx.x;
    int node = (int)(idx / FO);
    int f = (int)(idx % FO);
    if (node < n) {
        float d = dis[node];
        float v = agg[idx] + hw[idx] * (d * d) + b[f];
        agg[idx] = RELU ? fmaxf(v, 0.0f) : v;
    }
}

// ---------------- pooling ----------------

__global__ void pool_kernel(const float* __restrict__ h, const int* __restrict__ batch,
                            float* __restrict__ pooled, float* __restrict__ counts, int n) {
    long long idx = (long long)blockIdx.x * blockDim.x + threadIdx.x;
    int node = (int)(idx >> 7);
    int f = (int)(idx & 127);
    if (node < n) {
        int g = batch[node];
        atomicAdd(&pooled[(size_t)g * 128 + f], h[(size_t)node * 128 + f]);
        if (f == 0) atomicAdd(&counts[g], 1.0f);
    }
}

// ---------------- MLP head: out = relu(pooled/c @ fw1 + fb1) @ fw2 + fb2 ----------------

__global__ void mlp_kernel(const float* __restrict__ pooled, const float* __restrict__ counts,
                           const float* __restrict__ fw1, const float* __restrict__ fb1,
                           const float* __restrict__ fw2, const float* __restrict__ fb2,
                           float* __restrict__ out) {
    __shared__ float sp[128];
    __shared__ float sh[64];
    int g = blockIdx.x;
    float c = fmaxf(counts[g], 1.0f);
    for (int i = threadIdx.x; i < 128; i += 64) sp[i] = pooled[(size_t)g * 128 + i] / c;
    __syncthreads();
    int j = threadIdx.x;  // 64 threads
    float acc = fb1[j];
#pragma unroll
    for (int k = 0; k < 128; ++k) acc += sp[k] * fw1[k * 64 + j];
    sh[j] = fmaxf(acc, 0.0f);
    __syncthreads();
    if (j < TGT) {
        float acc2 = fb2[j];
#pragma unroll
        for (int k = 0; k < 64; ++k) acc2 += sh[k] * fw2[k * TGT + j];
        out[(size_t)g * TGT + j] = acc2;
    }
}

extern "C" void kernel_launch(void* const* d_in, const int* in_sizes, int n_in,
                              void* d_out, int out_size, void* d_ws, size_t ws_size,
                              hipStream_t stream) {
    const float* x = (const float*)d_in[0];
    const int* edge_index = (const int*)d_in[1];
    const int* batch = (const int*)d_in[2];
    const float* W1 = (const float*)d_in[3];
    const float* b1 = (const float*)d_in[4];
    const float* W2 = (const float*)d_in[5];
    const float* b2 = (const float*)d_in[6];
    const float* W3 = (const float*)d_in[7];
    const float* b3 = (const float*)d_in[8];
    const float* fw1 = (const float*)d_in[9];
    const float* fb1 = (const float*)d_in[10];
    const float* fw2 = (const float*)d_in[11];
    const float* fb2 = (const float*)d_in[12];
    float* out = (float*)d_out;

    const int N = in_sizes[2];          // batch has N entries
    const int E = in_sizes[1] / 2;      // edge_index is [2, E]
    const int* src = edge_index;
    const int* dst = edge_index + E;

    // workspace layout (floats)
    float* ws = (float*)d_ws;
    float* dis = ws;                         // N (also deg scratch)
    float* enorm = dis + N;                  // E
    float* bufA = enorm + E;                 // N*128
    float* bufB = bufA + (size_t)N * 128;    // N*128
    float* bufC = bufB + (size_t)N * 128;    // N*128
    float* pooled = bufC + (size_t)N * 128;  // G*128
    float* counts = pooled + (size_t)GG * 128;  // G

    const int T = 256;
    auto cdiv = [](long long a, long long b) { return (int)((a + b - 1) / b); };

    // degree -> dis
    hipMemsetAsync(dis, 0, (size_t)N * sizeof(float), stream);
    deg_kernel<<<cdiv(E, T), T, 0, stream>>>(dst, dis, E);
    dis_kernel<<<cdiv(N, T), T, 0, stream>>>(dis, N);
    edge_norm_kernel<<<cdiv(E, T), T, 0, stream>>>(src, dst, dis, enorm, E);

    // ---- layer 1: x(11) -> 32, relu ----
    gemm_kernel<F_IN, 32><<<cdiv(N, 256 / 32), T, 0, stream>>>(x, W1, bufA, N);
    hipMemsetAsync(bufB, 0, (size_t)N * 32 * sizeof(float), stream);
    scatter_kernel<32><<<cdiv((long long)E * 32, T), T, 0, stream>>>(src, dst, enorm, bufA, bufB, E);
    finalize_kernel<32, true><<<cdiv((long long)N * 32, T), T, 0, stream>>>(bufA, dis, b1, bufB, N);

    // ---- layer 2: 32 -> 64, relu ----
    gemm_kernel<32, 64><<<cdiv(N, 256 / 64), T, 0, stream>>>(bufB, W2, bufA, N);
    hipMemsetAsync(bufC, 0, (size_t)N * 64 * sizeof(float), stream);
    scatter_kernel<64><<<cdiv((long long)E * 64, T), T, 0, stream>>>(src, dst, enorm, bufA, bufC, E);
    finalize_kernel<64, true><<<cdiv((long long)N * 64, T), T, 0, stream>>>(bufA, dis, b2, bufC, N);

    // ---- layer 3: 64 -> 128, no relu ----
    gemm_kernel<64, 128><<<cdiv(N, 256 / 128), T, 0, stream>>>(bufC, W3, bufA, N);
    hipMemsetAsync(bufB, 0, (size_t)N * 128 * sizeof(float), stream);
    scatter_kernel<128><<<cdiv((long long)E * 128, T), T, 0, stream>>>(src, dst, enorm, bufA, bufB, E);
    finalize_kernel<128, false><<<cdiv((long long)N * 128, T), T, 0, stream>>>(bufA, dis, b3, bufB, N);

    // ---- mean pool ----
    hipMemsetAsync(pooled, 0, (size_t)(GG * 128 + GG) * sizeof(float), stream);
    pool_kernel<<<cdiv((long long)N * 128, T), T, 0, stream>>>(bufB, batch, pooled, counts, N);

    // ---- MLP head ----
    mlp_kernel<<<GG, 64, 0, stream>>>(pooled, counts, fw1, fb1, fw2, fb2, out);
}

// Round 2
// 449.348 us; speedup vs baseline: 1.8486x; 1.8486x over previous
//
#include <hip/hip_runtime.h>
#include <hip/hip_bf16.h>

// GCN: 3x GCNConv (11->32->64->128) + mean-pool + MLP (128->64->12)
// N=50000 nodes, E=600000 edges, G=512 graphs.
//
// Strategy: aggregation commutes with the per-node linear map, so we
// aggregate at the INPUT width of each layer (11/32/64 instead of
// 32/64/128), and we build a CSR (dst-sorted edge list) on device each
// call so aggregation is a gather + register accumulate (no atomics).

#define GG 512
#define TGT 12

// ---------------- degree / normalization ----------------

__global__ void deg_count_kernel(const int* __restrict__ dst, int* __restrict__ cnt, int E) {
    int i = blockIdx.x * blockDim.x + threadIdx.x;
    if (i < E) atomicAdd(&cnt[dst[i]], 1);
}

__global__ void dis_kernel(const int* __restrict__ cnt, float* __restrict__ dis, int n) {
    int i = blockIdx.x * blockDim.x + threadIdx.x;
    if (i < n) dis[i] = rsqrtf(1.0f + (float)cnt[i]);
}

// ---------------- 2-level exclusive scan over counts ----------------

__global__ void scan1_kernel(const int* __restrict__ cnt, int* __restrict__ excl,
                             int* __restrict__ psum, int n) {
    __shared__ int sh[256];
    int i = blockIdx.x * 256 + threadIdx.x;
    int v = (i < n) ? cnt[i] : 0;
    sh[threadIdx.x] = v;
    __syncthreads();
    for (int off = 1; off < 256; off <<= 1) {
        int t = (threadIdx.x >= (unsigned)off) ? sh[threadIdx.x - off] : 0;
        __syncthreads();
        sh[threadIdx.x] += t;
        __syncthreads();
    }
    if (i < n) excl[i] = sh[threadIdx.x] - v;  // exclusive within block
    if (threadIdx.x == 255) psum[blockIdx.x] = sh[255];
}

__global__ void scan2_kernel(int* __restrict__ psum, int nb) {
    __shared__ int sh[256];
    int carry = 0;
    for (int base = 0; base < nb; base += 256) {
        int i = base + threadIdx.x;
        int v = (i < nb) ? psum[i] : 0;
        sh[threadIdx.x] = v;
        __syncthreads();
        for (int off = 1; off < 256; off <<= 1) {
            int t = (threadIdx.x >= (unsigned)off) ? sh[threadIdx.x - off] : 0;
            __syncthreads();
            sh[threadIdx.x] += t;
            __syncthreads();
        }
        if (i < nb) psum[i] = sh[threadIdx.x] - v + carry;  // exclusive + carry
        carry += sh[255];
        __syncthreads();
    }
}

__global__ void scan3_kernel(int* __restrict__ excl, const int* __restrict__ psum, int n) {
    int i = blockIdx.x * 256 + threadIdx.x;
    if (i < n) excl[i] += psum[blockIdx.x];
}

// ---------------- edge placement into CSR ----------------

__global__ void place_kernel(const int* __restrict__ src, const int* __restrict__ dst,
                             const int* __restrict__ excl, int* __restrict__ cursor,
                             int* __restrict__ esrc, int E) {
    int i = blockIdx.x * blockDim.x + threadIdx.x;
    if (i < E) {
        int d = dst[i];
        int pos = excl[d] + atomicAdd(&cursor[d], 1);
        esrc[pos] = src[i];
    }
}

// ---------------- gather aggregation: hhat[n] = sum_in h[s]*dis[s]*dis[n] + h[n]*dis[n]^2 ----------------

template <int F, int FP>
__global__ void agg_kernel(const float* __restrict__ h, const float* __restrict__ dis,
                           const int* __restrict__ offs, const int* __restrict__ cnt,
                           const int* __restrict__ esrc, float* __restrict__ out, int n) {
    constexpr int NPB = 256 / FP;
    int node = blockIdx.x * NPB + (int)(threadIdx.x / FP);
    int lane = threadIdx.x % FP;
    if (node >= n) return;
    float dn = dis[node];
    float acc = 0.0f;
    if (lane < F) acc = h[(size_t)node * F + lane] * dn * dn;
    int s0 = offs[node], c = cnt[node];
    for (int e = 0; e < c; ++e) {
        int s = esrc[s0 + e];
        float w = dis[s] * dn;
        if (lane < F) acc += h[(size_t)s * F + lane] * w;
    }
    if (lane < F) out[(size_t)node * F + lane] = acc;
}

// ---------------- dense GEMM with fused bias(+relu): out = [relu](h @ W + b) ----------------

template <int FI, int FO, bool RELU>
__global__ void gemm_bias_kernel(const float* __restrict__ h, const float* __restrict__ W,
                                 const float* __restrict__ b, float* __restrict__ out, int n) {
    __shared__ float sW[FI * FO];
    for (int i = threadIdx.x; i < FI * FO; i += blockDim.x) sW[i] = W[i];
    __syncthreads();
    constexpr int NPB = 256 / FO;
    int node = blockIdx.x * NPB + (int)(threadIdx.x / FO);
    int fo = threadIdx.x % FO;
    if (node < n) {
        const float* row = h + (size_t)node * FI;
        float acc = b[fo];
#pragma unroll
        for (int fi = 0; fi < FI; ++fi) acc += row[fi] * sW[fi * FO + fo];
        out[(size_t)node * FO + fo] = RELU ? fmaxf(acc, 0.0f) : acc;
    }
}

// ---------------- layer-3 GEMM fused with mean-pool accumulation ----------------

template <int FI, int FO>
__global__ void gemm_pool_kernel(const float* __restrict__ h, const float* __restrict__ W,
                                 const float* __restrict__ b, const int* __restrict__ batch,
                                 float* __restrict__ pooled, int n) {
    __shared__ float sW[FI * FO];
    for (int i = threadIdx.x; i < FI * FO; i += blockDim.x) sW[i] = W[i];
    __syncthreads();
    constexpr int NPB = 256 / FO;
    int node = blockIdx.x * NPB + (int)(threadIdx.x / FO);
    int fo = threadIdx.x % FO;
    if (node < n) {
        const float* row = h + (size_t)node * FI;
        float acc = b[fo];
#pragma unroll
        for (int fi = 0; fi < FI; ++fi) acc += row[fi] * sW[fi * FO + fo];
        atomicAdd(&pooled[(size_t)batch[node] * FO + fo], acc);
    }
}

__global__ void counts_kernel(const int* __restrict__ batch, float* __restrict__ counts, int n) {
    int i = blockIdx.x * blockDim.x + threadIdx.x;
    if (i < n) atomicAdd(&counts[batch[i]], 1.0f);
}

// ---------------- MLP head: out = relu(pooled/c @ fw1 + fb1) @ fw2 + fb2 ----------------

__global__ void mlp_kernel(const float* __restrict__ pooled, const float* __restrict__ counts,
                           const float* __restrict__ fw1, const float* __restrict__ fb1,
                           const float* __restrict__ fw2, const float* __restrict__ fb2,
                           float* __restrict__ out) {
    __shared__ float sp[128];
    __shared__ float sh[64];
    int g = blockIdx.x;
    float c = fmaxf(counts[g], 1.0f);
    for (int i = threadIdx.x; i < 128; i += 64) sp[i] = pooled[(size_t)g * 128 + i] / c;
    __syncthreads();
    int j = threadIdx.x;  // 64 threads
    float acc = fb1[j];
#pragma unroll
    for (int k = 0; k < 128; ++k) acc += sp[k] * fw1[k * 64 + j];
    sh[j] = fmaxf(acc, 0.0f);
    __syncthreads();
    if (j < TGT) {
        float acc2 = fb2[j];
#pragma unroll
        for (int k = 0; k < 64; ++k) acc2 += sh[k] * fw2[k * TGT + j];
        out[(size_t)g * TGT + j] = acc2;
    }
}

extern "C" void kernel_launch(void* const* d_in, const int* in_sizes, int n_in,
                              void* d_out, int out_size, void* d_ws, size_t ws_size,
                              hipStream_t stream) {
    const float* x = (const float*)d_in[0];
    const int* edge_index = (const int*)d_in[1];
    const int* batch = (const int*)d_in[2];
    const float* W1 = (const float*)d_in[3];
    const float* b1 = (const float*)d_in[4];
    const float* W2 = (const float*)d_in[5];
    const float* b2 = (const float*)d_in[6];
    const float* W3 = (const float*)d_in[7];
    const float* b3 = (const float*)d_in[8];
    const float* fw1 = (const float*)d_in[9];
    const float* fb1 = (const float*)d_in[10];
    const float* fw2 = (const float*)d_in[11];
    const float* fb2 = (const float*)d_in[12];
    float* out = (float*)d_out;

    const int N = in_sizes[2];
    const int E = in_sizes[1] / 2;
    const int* src = edge_index;
    const int* dst = edge_index + E;

    // workspace layout
    float* dis = (float*)d_ws;                   // N
    int* incnt = (int*)(dis + N);                // N
    int* excl = incnt + N;                       // N
    int* cursor = excl + N;                      // N
    int* psum = cursor + N;                      // 256
    int* esrc = psum + 256;                      // E
    float* bufA = (float*)(esrc + E);            // N*64
    float* bufB = bufA + (size_t)N * 64;         // N*64
    float* pooled = bufB + (size_t)N * 64;       // G*128
    float* counts = pooled + (size_t)GG * 128;   // G

    const int T = 256;
    auto cdiv = [](long long a, long long b) { return (int)((a + b - 1) / b); };
    const int nb1 = cdiv(N, 256);

    // ---- CSR build ----
    hipMemsetAsync(incnt, 0, (size_t)N * sizeof(int), stream);
    deg_count_kernel<<<cdiv(E, T), T, 0, stream>>>(dst, incnt, E);
    dis_kernel<<<cdiv(N, T), T, 0, stream>>>(incnt, dis, N);
    scan1_kernel<<<nb1, 256, 0, stream>>>(incnt, excl, psum, N);
    scan2_kernel<<<1, 256, 0, stream>>>(psum, nb1);
    scan3_kernel<<<nb1, 256, 0, stream>>>(excl, psum, N);
    hipMemsetAsync(cursor, 0, (size_t)N * sizeof(int), stream);
    place_kernel<<<cdiv(E, T), T, 0, stream>>>(src, dst, excl, cursor, esrc, E);

    // ---- layer 1: agg(x)@W1 + b1, relu ----
    agg_kernel<11, 16><<<cdiv(N, 16), T, 0, stream>>>(x, dis, excl, incnt, esrc, bufA, N);
    gemm_bias_kernel<11, 32, true><<<cdiv(N, 8), T, 0, stream>>>(bufA, W1, b1, bufB, N);

    // ---- layer 2: agg(h1)@W2 + b2, relu ----
    agg_kernel<32, 32><<<cdiv(N, 8), T, 0, stream>>>(bufB, dis, excl, incnt, esrc, bufA, N);
    gemm_bias_kernel<32, 64, true><<<cdiv(N, 4), T, 0, stream>>>(bufA, W2, b2, bufB, N);

    // ---- layer 3: agg(h2)@W3 + b3, fused mean-pool accumulate ----
    agg_kernel<64, 64><<<cdiv(N, 4), T, 0, stream>>>(bufB, dis, excl, incnt, esrc, bufA, N);
    hipMemsetAsync(pooled, 0, (size_t)(GG * 128 + GG) * sizeof(float), stream);
    gemm_pool_kernel<64, 128><<<cdiv(N, 2), T, 0, stream>>>(bufA, W3, b3, batch, pooled, N);
    counts_kernel<<<cdiv(N, T), T, 0, stream>>>(batch, counts, N);

    // ---- MLP head ----
    mlp_kernel<<<GG, 64, 0, stream>>>(pooled, counts, fw1, fb1, fw2, fb2, out);
}

// Round 3
// 377.959 us; speedup vs baseline: 2.1977x; 1.1889x over previous
//
#include <hip/hip_runtime.h>
#include <hip/hip_bf16.h>

// GCN: 3x GCNConv (11->32->64->128) + mean-pool + MLP (128->64->12)
// N=50000, E=600000, G=512. Aggregate-before-GEMM + on-device CSR.
// Pooling uses register accumulation over the sorted batch vector.

#define GG 512
#define TGT 12

// ---------------- degree / normalization ----------------

__global__ void deg_count_kernel(const int* __restrict__ dst, int* __restrict__ cnt, int E) {
    int i = blockIdx.x * blockDim.x + threadIdx.x;
    if (i < E) atomicAdd(&cnt[dst[i]], 1);
}

__global__ void dis_kernel(const int* __restrict__ cnt, float* __restrict__ dis, int n) {
    int i = blockIdx.x * blockDim.x + threadIdx.x;
    if (i < n) dis[i] = rsqrtf(1.0f + (float)cnt[i]);
}

// ---------------- 2-level exclusive scan over counts ----------------

__global__ void scan1_kernel(const int* __restrict__ cnt, int* __restrict__ excl,
                             int* __restrict__ psum, int n) {
    __shared__ int sh[256];
    int i = blockIdx.x * 256 + threadIdx.x;
    int v = (i < n) ? cnt[i] : 0;
    sh[threadIdx.x] = v;
    __syncthreads();
    for (int off = 1; off < 256; off <<= 1) {
        int t = (threadIdx.x >= (unsigned)off) ? sh[threadIdx.x - off] : 0;
        __syncthreads();
        sh[threadIdx.x] += t;
        __syncthreads();
    }
    if (i < n) excl[i] = sh[threadIdx.x] - v;
    if (threadIdx.x == 255) psum[blockIdx.x] = sh[255];
}

__global__ void scan2_kernel(int* __restrict__ psum, int nb) {
    __shared__ int sh[256];
    int carry = 0;
    for (int base = 0; base < nb; base += 256) {
        int i = base + threadIdx.x;
        int v = (i < nb) ? psum[i] : 0;
        sh[threadIdx.x] = v;
        __syncthreads();
        for (int off = 1; off < 256; off <<= 1) {
            int t = (threadIdx.x >= (unsigned)off) ? sh[threadIdx.x - off] : 0;
            __syncthreads();
            sh[threadIdx.x] += t;
            __syncthreads();
        }
        if (i < nb) psum[i] = sh[threadIdx.x] - v + carry;
        carry += sh[255];
        __syncthreads();
    }
}

__global__ void scan3_kernel(int* __restrict__ excl, const int* __restrict__ psum, int n) {
    int i = blockIdx.x * 256 + threadIdx.x;
    if (i < n) excl[i] += psum[blockIdx.x];
}

// ---------------- edge placement into CSR ----------------

__global__ void place_kernel(const int* __restrict__ src, const int* __restrict__ dst,
                             const int* __restrict__ excl, int* __restrict__ cursor,
                             int* __restrict__ esrc, int E) {
    int i = blockIdx.x * blockDim.x + threadIdx.x;
    if (i < E) {
        int d = dst[i];
        int pos = excl[d] + atomicAdd(&cursor[d], 1);
        esrc[pos] = src[i];
    }
}

// ---------------- scale x by dis: hs = x * dis[node] ----------------

__global__ void scale_x_kernel(const float* __restrict__ x, const float* __restrict__ dis,
                               float* __restrict__ hs, int n) {
    long long idx = (long long)blockIdx.x * blockDim.x + threadIdx.x;
    int node = (int)(idx >> 4);
    int lane = (int)(idx & 15);
    if (node < n && lane < 11)
        hs[(size_t)node * 11 + lane] = x[(size_t)node * 11 + lane] * dis[node];
}

// ---- gather aggregation on pre-scaled features:
//      out[n] = dis[n] * ( sum_in hs[s] + hs[n] )  ----

template <int F, int FP>
__global__ void agg_kernel(const float* __restrict__ hs, const float* __restrict__ dis,
                           const int* __restrict__ offs, const int* __restrict__ cnt,
                           const int* __restrict__ esrc, float* __restrict__ out, int n) {
    constexpr int NPB = 256 / FP;
    int node = blockIdx.x * NPB + (int)(threadIdx.x / FP);
    int lane = threadIdx.x % FP;
    if (node >= n) return;
    float acc = 0.0f;
    if (lane < F) acc = hs[(size_t)node * F + lane];
    int s0 = offs[node], c = cnt[node];
    for (int e = 0; e < c; ++e) {
        int s = esrc[s0 + e];
        if (lane < F) acc += hs[(size_t)s * F + lane];
    }
    if (lane < F) out[(size_t)node * F + lane] = acc * dis[node];
}

// ---- dense GEMM, fused bias+relu, output pre-scaled by dis for next agg ----

template <int FI, int FO>
__global__ void gemm_bias_scale_kernel(const float* __restrict__ h, const float* __restrict__ W,
                                       const float* __restrict__ b, const float* __restrict__ dis,
                                       float* __restrict__ out, int n) {
    __shared__ float sW[FI * FO];
    for (int i = threadIdx.x; i < FI * FO; i += blockDim.x) sW[i] = W[i];
    __syncthreads();
    constexpr int NPB = 256 / FO;
    int node = blockIdx.x * NPB + (int)(threadIdx.x / FO);
    int fo = threadIdx.x % FO;
    if (node < n) {
        const float* row = h + (size_t)node * FI;
        float acc = b[fo];
#pragma unroll
        for (int fi = 0; fi < FI; ++fi) acc += row[fi] * sW[fi * FO + fo];
        out[(size_t)node * FO + fo] = fmaxf(acc, 0.0f) * dis[node];
    }
}

// ---- layer-3 GEMM fused with mean-pool: register accumulation over sorted batch ----

template <int FI, int FO, int CHUNK>
__global__ void gemm_pool_kernel(const float* __restrict__ h, const float* __restrict__ W,
                                 const float* __restrict__ b, const int* __restrict__ batch,
                                 float* __restrict__ pooled, int n) {
    __shared__ float sW[FI * FO];
    for (int i = threadIdx.x; i < FI * FO; i += blockDim.x) sW[i] = W[i];
    __syncthreads();
    constexpr int NPB = 256 / FO;  // nodes processed concurrently
    int fo = threadIdx.x % FO;
    int sub = threadIdx.x / FO;
    int base = blockIdx.x * CHUNK;
    float bias = b[fo];
    int g_cur = -1;
    float acc = 0.0f;
    for (int i = sub; i < CHUNK; i += NPB) {
        int node = base + i;
        if (node >= n) break;
        int g = batch[node];
        if (g != g_cur) {
            if (g_cur >= 0) atomicAdd(&pooled[(size_t)g_cur * FO + fo], acc);
            acc = 0.0f;
            g_cur = g;
        }
        const float* row = h + (size_t)node * FI;
        float v = bias;
#pragma unroll
        for (int fi = 0; fi < FI; ++fi) v += row[fi] * sW[fi * FO + fo];
        acc += v;
    }
    if (g_cur >= 0) atomicAdd(&pooled[(size_t)g_cur * FO + fo], acc);
}

// ---- per-graph node counts via binary search on sorted batch ----

__global__ void counts_kernel(const int* __restrict__ batch, float* __restrict__ counts, int n) {
    int g = blockIdx.x * blockDim.x + threadIdx.x;
    if (g >= GG) return;
    auto lb = [&](int key) {
        int lo = 0, hi = n;
        while (lo < hi) {
            int mid = (lo + hi) >> 1;
            if (batch[mid] < key) lo = mid + 1; else hi = mid;
        }
        return lo;
    };
    counts[g] = (float)(lb(g + 1) - lb(g));
}

// ---------------- MLP head ----------------

__global__ void mlp_kernel(const float* __restrict__ pooled, const float* __restrict__ counts,
                           const float* __restrict__ fw1, const float* __restrict__ fb1,
                           const float* __restrict__ fw2, const float* __restrict__ fb2,
                           float* __restrict__ out) {
    __shared__ float sp[128];
    __shared__ float sh[64];
    int g = blockIdx.x;
    float c = fmaxf(counts[g], 1.0f);
    for (int i = threadIdx.x; i < 128; i += 64) sp[i] = pooled[(size_t)g * 128 + i] / c;
    __syncthreads();
    int j = threadIdx.x;
    float acc = fb1[j];
#pragma unroll
    for (int k = 0; k < 128; ++k) acc += sp[k] * fw1[k * 64 + j];
    sh[j] = fmaxf(acc, 0.0f);
    __syncthreads();
    if (j < TGT) {
        float acc2 = fb2[j];
#pragma unroll
        for (int k = 0; k < 64; ++k) acc2 += sh[k] * fw2[k * TGT + j];
        out[(size_t)g * TGT + j] = acc2;
    }
}

extern "C" void kernel_launch(void* const* d_in, const int* in_sizes, int n_in,
                              void* d_out, int out_size, void* d_ws, size_t ws_size,
                              hipStream_t stream) {
    const float* x = (const float*)d_in[0];
    const int* edge_index = (const int*)d_in[1];
    const int* batch = (const int*)d_in[2];
    const float* W1 = (const float*)d_in[3];
    const float* b1 = (const float*)d_in[4];
    const float* W2 = (const float*)d_in[5];
    const float* b2 = (const float*)d_in[6];
    const float* W3 = (const float*)d_in[7];
    const float* b3 = (const float*)d_in[8];
    const float* fw1 = (const float*)d_in[9];
    const float* fb1 = (const float*)d_in[10];
    const float* fw2 = (const float*)d_in[11];
    const float* fb2 = (const float*)d_in[12];
    float* out = (float*)d_out;

    const int N = in_sizes[2];
    const int E = in_sizes[1] / 2;
    const int* src = edge_index;
    const int* dst = edge_index + E;

    // workspace layout
    float* dis = (float*)d_ws;                   // N
    int* incnt = (int*)(dis + N);                // N
    int* excl = incnt + N;                       // N
    int* cursor = excl + N;                      // N
    int* psum = cursor + N;                      // 256
    int* esrc = psum + 256;                      // E
    float* bufA = (float*)(esrc + E);            // N*64
    float* bufB = bufA + (size_t)N * 64;         // N*64
    float* pooled = bufB + (size_t)N * 64;       // G*128
    float* counts = pooled + (size_t)GG * 128;   // G

    const int T = 256;
    auto cdiv = [](long long a, long long b) { return (int)((a + b - 1) / b); };
    const int nb1 = cdiv(N, 256);

    // ---- CSR build ----
    hipMemsetAsync(incnt, 0, (size_t)N * sizeof(int), stream);
    deg_count_kernel<<<cdiv(E, T), T, 0, stream>>>(dst, incnt, E);
    dis_kernel<<<cdiv(N, T), T, 0, stream>>>(incnt, dis, N);
    scan1_kernel<<<nb1, 256, 0, stream>>>(incnt, excl, psum, N);
    scan2_kernel<<<1, 256, 0, stream>>>(psum, nb1);
    scan3_kernel<<<nb1, 256, 0, stream>>>(excl, psum, N);
    hipMemsetAsync(cursor, 0, (size_t)N * sizeof(int), stream);
    place_kernel<<<cdiv(E, T), T, 0, stream>>>(src, dst, excl, cursor, esrc, E);

    // ---- layer 1 ----
    scale_x_kernel<<<cdiv((long long)N * 16, T), T, 0, stream>>>(x, dis, bufA, N);
    agg_kernel<11, 16><<<cdiv(N, 16), T, 0, stream>>>(bufA, dis, excl, incnt, esrc, bufB, N);
    gemm_bias_scale_kernel<11, 32><<<cdiv(N, 8), T, 0, stream>>>(bufB, W1, b1, dis, bufA, N);

    // ---- layer 2 ----
    agg_kernel<32, 32><<<cdiv(N, 8), T, 0, stream>>>(bufA, dis, excl, incnt, esrc, bufB, N);
    gemm_bias_scale_kernel<32, 64><<<cdiv(N, 4), T, 0, stream>>>(bufB, W2, b2, dis, bufA, N);

    // ---- layer 3 ----
    agg_kernel<64, 64><<<cdiv(N, 4), T, 0, stream>>>(bufA, dis, excl, incnt, esrc, bufB, N);
    hipMemsetAsync(pooled, 0, (size_t)(GG * 128 + GG) * sizeof(float), stream);
    gemm_pool_kernel<64, 128, 128><<<cdiv(N, 128), T, 0, stream>>>(bufB, W3, b3, batch, pooled, N);
    counts_kernel<<<2, 256, 0, stream>>>(batch, counts, N);

    // ---- MLP head ----
    mlp_kernel<<<GG, 64, 0, stream>>>(pooled, counts, fw1, fb1, fw2, fb2, out);
}

// Round 4
// 204.172 us; speedup vs baseline: 4.0684x; 1.8512x over previous
//
#include <hip/hip_runtime.h>
#include <hip/hip_bf16.h>

// GCN: 3x GCNConv (11->32->64->128) + mean-pool + MLP (128->64->12)
// N=50000, E=600000, G=512.
// - aggregate-before-GEMM (agg at widths 16(pad)/32/64)
// - on-device CSR, gather aggregation (no atomics), float4 lanes
// - pool-before-GEMM for layer 3 (GEMM is linear, no relu before pooling)
// - per-graph binary-search pooling on sorted batch (no atomics)

#define GG 512
#define TGT 12

// ---------------- degree / normalization ----------------

__global__ void deg_count_kernel(const int* __restrict__ dst, int* __restrict__ cnt, int E) {
    int i = blockIdx.x * blockDim.x + threadIdx.x;
    if (i < E) atomicAdd(&cnt[dst[i]], 1);
}

__global__ void dis_kernel(const int* __restrict__ cnt, float* __restrict__ dis, int n) {
    int i = blockIdx.x * blockDim.x + threadIdx.x;
    if (i < n) dis[i] = rsqrtf(1.0f + (float)cnt[i]);
}

// ---------------- 2-level exclusive scan over counts ----------------

__global__ void scan1_kernel(const int* __restrict__ cnt, int* __restrict__ excl,
                             int* __restrict__ psum, int n) {
    __shared__ int sh[256];
    int i = blockIdx.x * 256 + threadIdx.x;
    int v = (i < n) ? cnt[i] : 0;
    sh[threadIdx.x] = v;
    __syncthreads();
    for (int off = 1; off < 256; off <<= 1) {
        int t = (threadIdx.x >= (unsigned)off) ? sh[threadIdx.x - off] : 0;
        __syncthreads();
        sh[threadIdx.x] += t;
        __syncthreads();
    }
    if (i < n) excl[i] = sh[threadIdx.x] - v;
    if (threadIdx.x == 255) psum[blockIdx.x] = sh[255];
}

__global__ void scan2_kernel(int* __restrict__ psum, int nb) {
    __shared__ int sh[256];
    int carry = 0;
    for (int base = 0; base < nb; base += 256) {
        int i = base + threadIdx.x;
        int v = (i < nb) ? psum[i] : 0;
        sh[threadIdx.x] = v;
        __syncthreads();
        for (int off = 1; off < 256; off <<= 1) {
            int t = (threadIdx.x >= (unsigned)off) ? sh[threadIdx.x - off] : 0;
            __syncthreads();
            sh[threadIdx.x] += t;
            __syncthreads();
        }
        if (i < nb) psum[i] = sh[threadIdx.x] - v + carry;
        carry += sh[255];
        __syncthreads();
    }
}

__global__ void scan3_kernel(int* __restrict__ excl, const int* __restrict__ psum, int n) {
    int i = blockIdx.x * 256 + threadIdx.x;
    if (i < n) excl[i] += psum[blockIdx.x];
}

// ---------------- edge placement into CSR ----------------

__global__ void place_kernel(const int* __restrict__ src, const int* __restrict__ dst,
                             const int* __restrict__ excl, int* __restrict__ cursor,
                             int* __restrict__ esrc, int E) {
    int i = blockIdx.x * blockDim.x + threadIdx.x;
    if (i < E) {
        int d = dst[i];
        int pos = excl[d] + atomicAdd(&cursor[d], 1);
        esrc[pos] = src[i];
    }
}

// ---------------- scale x by dis into 16-padded rows ----------------

__global__ void scale_x_kernel(const float* __restrict__ x, const float* __restrict__ dis,
                               float* __restrict__ hs, int n) {
    long long idx = (long long)blockIdx.x * blockDim.x + threadIdx.x;
    int node = (int)(idx >> 4);
    int lane = (int)(idx & 15);
    if (node < n)
        hs[(size_t)node * 16 + lane] =
            (lane < 11) ? x[(size_t)node * 11 + lane] * dis[node] : 0.0f;
}

// ---- gather aggregation (float4 lanes) on pre-scaled features:
//      out[n] = dis[n] * ( sum_in hs[s] + hs[n] )  ----

template <int F>  // floats per row, multiple of 4
__global__ void agg4_kernel(const float4* __restrict__ hs, const float* __restrict__ dis,
                            const int* __restrict__ offs, const int* __restrict__ cnt,
                            const int* __restrict__ esrc, float4* __restrict__ out, int n) {
    constexpr int LP = F / 4;        // lanes per node
    constexpr int NPB = 256 / LP;    // nodes per block
    int node = blockIdx.x * NPB + (int)(threadIdx.x / LP);
    int lane = threadIdx.x % LP;
    if (node >= n) return;
    float4 acc = hs[(size_t)node * LP + lane];
    int s0 = offs[node], c = cnt[node];
    for (int e = 0; e < c; ++e) {
        int s = esrc[s0 + e];
        float4 v = hs[(size_t)s * LP + lane];
        acc.x += v.x; acc.y += v.y; acc.z += v.z; acc.w += v.w;
    }
    float dn = dis[node];
    float4 r;
    r.x = acc.x * dn; r.y = acc.y * dn; r.z = acc.z * dn; r.w = acc.w * dn;
    out[(size_t)node * LP + lane] = r;
}

// ---- dense GEMM, fused bias+relu, output pre-scaled by dis for next agg ----

template <int FI, int STRIDE, int FO>
__global__ void gemm_bias_scale_kernel(const float* __restrict__ h, const float* __restrict__ W,
                                       const float* __restrict__ b, const float* __restrict__ dis,
                                       float* __restrict__ out, int n) {
    __shared__ float sW[FI * FO];
    for (int i = threadIdx.x; i < FI * FO; i += blockDim.x) sW[i] = W[i];
    __syncthreads();
    constexpr int NPB = 256 / FO;
    int node = blockIdx.x * NPB + (int)(threadIdx.x / FO);
    int fo = threadIdx.x % FO;
    if (node < n) {
        const float* row = h + (size_t)node * STRIDE;
        float acc = b[fo];
#pragma unroll
        for (int fi = 0; fi < FI; ++fi) acc += row[fi] * sW[fi * FO + fo];
        out[(size_t)node * FO + fo] = fmaxf(acc, 0.0f) * dis[node];
    }
}

// ---- per-graph 64-wide sum over sorted batch (binary search, no atomics) ----

__global__ void pool_kernel(const float* __restrict__ h, const int* __restrict__ batch,
                            float* __restrict__ pooled, float* __restrict__ counts, int n) {
    int g = blockIdx.x;
    // all threads redundantly binary-search the graph's node range
    auto lb = [&](int key) {
        int lo = 0, hi = n;
        while (lo < hi) {
            int mid = (lo + hi) >> 1;
            if (batch[mid] < key) lo = mid + 1; else hi = mid;
        }
        return lo;
    };
    int lo = lb(g), hi = lb(g + 1);
    int fo = threadIdx.x & 63;
    int sub = threadIdx.x >> 6;  // 0..3
    float acc = 0.0f;
    for (int i = lo + sub; i < hi; i += 4) acc += h[(size_t)i * 64 + fo];
    __shared__ float red[4][64];
    red[sub][fo] = acc;
    __syncthreads();
    if (sub == 0) {
        pooled[(size_t)g * 64 + fo] = red[0][fo] + red[1][fo] + red[2][fo] + red[3][fo];
        if (fo == 0) counts[g] = (float)(hi - lo);
    }
}

// ---- fused head: p128 = (pooled/c)@W3 + b3; h64 = relu(p128@fw1+fb1); out = h64@fw2+fb2 ----

__global__ void head_kernel(const float* __restrict__ pooled, const float* __restrict__ counts,
                            const float* __restrict__ W3, const float* __restrict__ b3,
                            const float* __restrict__ fw1, const float* __restrict__ fb1,
                            const float* __restrict__ fw2, const float* __restrict__ fb2,
                            float* __restrict__ out) {
    int g = blockIdx.x;
    __shared__ float sp[64];
    __shared__ float p128[128];
    __shared__ float h64[64];
    float c = counts[g];
    float inv = (c > 0.0f) ? 1.0f / c : 0.0f;
    int j = threadIdx.x;  // 0..127
    if (j < 64) sp[j] = pooled[(size_t)g * 64 + j] * inv;
    __syncthreads();
    {
        float acc = (c > 0.0f) ? b3[j] : 0.0f;  // empty graph: reference pooled128 = 0
#pragma unroll
        for (int k = 0; k < 64; ++k) acc += sp[k] * W3[k * 128 + j];
        p128[j] = acc;
    }
    __syncthreads();
    if (j < 64) {
        float acc = fb1[j];
#pragma unroll
        for (int k = 0; k < 128; ++k) acc += p128[k] * fw1[k * 64 + j];
        h64[j] = fmaxf(acc, 0.0f);
    }
    __syncthreads();
    if (j < TGT) {
        float acc = fb2[j];
#pragma unroll
        for (int k = 0; k < 64; ++k) acc += h64[k] * fw2[k * TGT + j];
        out[(size_t)g * TGT + j] = acc;
    }
}

extern "C" void kernel_launch(void* const* d_in, const int* in_sizes, int n_in,
                              void* d_out, int out_size, void* d_ws, size_t ws_size,
                              hipStream_t stream) {
    const float* x = (const float*)d_in[0];
    const int* edge_index = (const int*)d_in[1];
    const int* batch = (const int*)d_in[2];
    const float* W1 = (const float*)d_in[3];
    const float* b1 = (const float*)d_in[4];
    const float* W2 = (const float*)d_in[5];
    const float* b2 = (const float*)d_in[6];
    const float* W3 = (const float*)d_in[7];
    const float* b3 = (const float*)d_in[8];
    const float* fw1 = (const float*)d_in[9];
    const float* fb1 = (const float*)d_in[10];
    const float* fw2 = (const float*)d_in[11];
    const float* fb2 = (const float*)d_in[12];
    float* out = (float*)d_out;

    const int N = in_sizes[2];
    const int E = in_sizes[1] / 2;
    const int* src = edge_index;
    const int* dst = edge_index + E;

    // workspace layout
    float* dis = (float*)d_ws;                   // N
    int* incnt = (int*)(dis + N);                // N
    int* excl = incnt + N;                       // N
    int* cursor = excl + N;                      // N
    int* psum = cursor + N;                      // 256
    int* esrc = psum + 256;                      // E
    float* bufA = (float*)(esrc + E);            // N*64
    float* bufB = bufA + (size_t)N * 64;         // N*64
    float* pooled = bufB + (size_t)N * 64;       // G*64
    float* counts = pooled + (size_t)GG * 64;    // G

    const int T = 256;
    auto cdiv = [](long long a, long long b) { return (int)((a + b - 1) / b); };
    const int nb1 = cdiv(N, 256);

    // ---- CSR build ----
    hipMemsetAsync(incnt, 0, (size_t)N * sizeof(int), stream);
    deg_count_kernel<<<cdiv(E, T), T, 0, stream>>>(dst, incnt, E);
    dis_kernel<<<cdiv(N, T), T, 0, stream>>>(incnt, dis, N);
    scan1_kernel<<<nb1, 256, 0, stream>>>(incnt, excl, psum, N);
    scan2_kernel<<<1, 256, 0, stream>>>(psum, nb1);
    scan3_kernel<<<nb1, 256, 0, stream>>>(excl, psum, N);
    hipMemsetAsync(cursor, 0, (size_t)N * sizeof(int), stream);
    place_kernel<<<cdiv(E, T), T, 0, stream>>>(src, dst, excl, cursor, esrc, E);

    // ---- layer 1: pad+scale, agg(16), gemm 11->32 ----
    scale_x_kernel<<<cdiv((long long)N * 16, T), T, 0, stream>>>(x, dis, bufA, N);
    agg4_kernel<16><<<cdiv(N, 64), T, 0, stream>>>((const float4*)bufA, dis, excl, incnt, esrc,
                                                   (float4*)bufB, N);
    gemm_bias_scale_kernel<11, 16, 32><<<cdiv(N, 8), T, 0, stream>>>(bufB, W1, b1, dis, bufA, N);

    // ---- layer 2: agg(32), gemm 32->64 ----
    agg4_kernel<32><<<cdiv(N, 32), T, 0, stream>>>((const float4*)bufA, dis, excl, incnt, esrc,
                                                   (float4*)bufB, N);
    gemm_bias_scale_kernel<32, 32, 64><<<cdiv(N, 4), T, 0, stream>>>(bufB, W2, b2, dis, bufA, N);

    // ---- layer 3: agg(64), then pool-before-GEMM ----
    agg4_kernel<64><<<cdiv(N, 16), T, 0, stream>>>((const float4*)bufA, dis, excl, incnt, esrc,
                                                   (float4*)bufB, N);
    pool_kernel<<<GG, 256, 0, stream>>>(bufB, batch, pooled, counts, N);

    // ---- fused W3 + MLP head ----
    head_kernel<<<GG, 128, 0, stream>>>(pooled, counts, W3, b3, fw1, fb1, fw2, fb2, out);
}

// Round 5
// 170.294 us; speedup vs baseline: 4.8777x; 1.1989x over previous
//
#include <hip/hip_runtime.h>
#include <hip/hip_bf16.h>

// GCN: 3x GCNConv (11->32->64->128) + mean-pool + MLP (128->64->12)
// N=50000, E=600000, G=512.
// - aggregate-before-GEMM (agg widths 16(pad)/32/64), pool-before-GEMM for L3
// - on-device CSR (no scan3: offs = excl[i] + psum[i>>8])
// - fused kernels: {dis+scale}, {agg+GEMM} x2, {agg64}, {pool+W3+MLP}

#define GG 512
#define TGT 12

// ---------------- degree count ----------------

__global__ void deg_count_kernel(const int* __restrict__ dst, int* __restrict__ cnt, int E) {
    int i = blockIdx.x * blockDim.x + threadIdx.x;
    if (i < E) atomicAdd(&cnt[dst[i]], 1);
}

// ---------------- dis + padded/scaled x, fused ----------------

__global__ void dis_scale_kernel(const int* __restrict__ cnt, const float* __restrict__ x,
                                 float* __restrict__ dis, float* __restrict__ hs, int n) {
    long long idx = (long long)blockIdx.x * blockDim.x + threadIdx.x;
    int node = (int)(idx >> 4);
    int lane = (int)(idx & 15);
    if (node >= n) return;
    float d = rsqrtf(1.0f + (float)cnt[node]);
    if (lane == 0) dis[node] = d;
    hs[(size_t)node * 16 + lane] = (lane < 11) ? x[(size_t)node * 11 + lane] * d : 0.0f;
}

// ---------------- scan: block-exclusive + block sums, then scan of sums ----------------

__global__ void scan1_kernel(const int* __restrict__ cnt, int* __restrict__ excl,
                             int* __restrict__ psum, int n) {
    __shared__ int sh[256];
    int i = blockIdx.x * 256 + threadIdx.x;
    int v = (i < n) ? cnt[i] : 0;
    sh[threadIdx.x] = v;
    __syncthreads();
    for (int off = 1; off < 256; off <<= 1) {
        int t = (threadIdx.x >= (unsigned)off) ? sh[threadIdx.x - off] : 0;
        __syncthreads();
        sh[threadIdx.x] += t;
        __syncthreads();
    }
    if (i < n) excl[i] = sh[threadIdx.x] - v;  // exclusive within block
    if (threadIdx.x == 255) psum[blockIdx.x] = sh[255];
}

__global__ void scan2_kernel(int* __restrict__ psum, int nb) {
    __shared__ int sh[256];
    int carry = 0;
    for (int base = 0; base < nb; base += 256) {
        int i = base + threadIdx.x;
        int v = (i < nb) ? psum[i] : 0;
        sh[threadIdx.x] = v;
        __syncthreads();
        for (int off = 1; off < 256; off <<= 1) {
            int t = (threadIdx.x >= (unsigned)off) ? sh[threadIdx.x - off] : 0;
            __syncthreads();
            sh[threadIdx.x] += t;
            __syncthreads();
        }
        if (i < nb) psum[i] = sh[threadIdx.x] - v + carry;
        carry += sh[255];
        __syncthreads();
    }
}

// ---------------- edge placement into CSR ----------------

__global__ void place_kernel(const int* __restrict__ src, const int* __restrict__ dst,
                             const int* __restrict__ excl, const int* __restrict__ psum,
                             int* __restrict__ cursor, int* __restrict__ esrc, int E) {
    int i = blockIdx.x * blockDim.x + threadIdx.x;
    if (i < E) {
        int d = dst[i];
        int pos = excl[d] + psum[d >> 8] + atomicAdd(&cursor[d], 1);
        esrc[pos] = src[i];
    }
}

// ---- fused agg + GEMM:  srow = dis[n]*(sum_in hs[s] + hs[n]);  out = relu(srow@W+b)*dis ----
// F: agg width (mult of 4); FI: true input width; FO: output width.

template <int F, int FI, int FO>
__global__ void aggemm_kernel(const float4* __restrict__ hs, const float* __restrict__ dis,
                              const int* __restrict__ excl, const int* __restrict__ psum,
                              const int* __restrict__ cnt, const int* __restrict__ esrc,
                              const float* __restrict__ W, const float* __restrict__ b,
                              float* __restrict__ out, int n) {
    constexpr int LP = F / 4;       // float4 lanes per node
    constexpr int NPB = 256 / LP;   // nodes per block
    __shared__ float srow[NPB][F];
    __shared__ float sdn[NPB];
    __shared__ float sW[FI * FO];
    for (int i = threadIdx.x; i < FI * FO; i += 256) sW[i] = W[i];

    int nd = threadIdx.x / LP;
    int lane = threadIdx.x % LP;
    int node = blockIdx.x * NPB + nd;
    if (node < n) {
        float4 acc = hs[(size_t)node * LP + lane];
        int s0 = excl[node] + psum[node >> 8];
        int c = cnt[node];
        for (int e = 0; e < c; ++e) {
            int s = esrc[s0 + e];
            float4 v = hs[(size_t)s * LP + lane];
            acc.x += v.x; acc.y += v.y; acc.z += v.z; acc.w += v.w;
        }
        float dn = dis[node];
        srow[nd][lane * 4 + 0] = acc.x * dn;
        srow[nd][lane * 4 + 1] = acc.y * dn;
        srow[nd][lane * 4 + 2] = acc.z * dn;
        srow[nd][lane * 4 + 3] = acc.w * dn;
        if (lane == 0) sdn[nd] = dn;
    }
    __syncthreads();

    int base = blockIdx.x * NPB;
#pragma unroll
    for (int o = threadIdx.x; o < NPB * FO; o += 256) {
        int fo = o % FO;
        int nd2 = o / FO;
        int node2 = base + nd2;
        if (node2 < n) {
            float acc = b[fo];
#pragma unroll
            for (int fi = 0; fi < FI; ++fi) acc += srow[nd2][fi] * sW[fi * FO + fo];
            out[(size_t)node2 * FO + fo] = fmaxf(acc, 0.0f) * sdn[nd2];
        }
    }
}

// ---- layer-3 aggregation (width 64), standalone ----

__global__ void agg64_kernel(const float4* __restrict__ hs, const float* __restrict__ dis,
                             const int* __restrict__ excl, const int* __restrict__ psum,
                             const int* __restrict__ cnt, const int* __restrict__ esrc,
                             float4* __restrict__ out, int n) {
    constexpr int LP = 16;
    constexpr int NPB = 16;
    int node = blockIdx.x * NPB + (int)(threadIdx.x / LP);
    int lane = threadIdx.x % LP;
    if (node >= n) return;
    float4 acc = hs[(size_t)node * LP + lane];
    int s0 = excl[node] + psum[node >> 8];
    int c = cnt[node];
    for (int e = 0; e < c; ++e) {
        int s = esrc[s0 + e];
        float4 v = hs[(size_t)s * LP + lane];
        acc.x += v.x; acc.y += v.y; acc.z += v.z; acc.w += v.w;
    }
    float dn = dis[node];
    float4 r;
    r.x = acc.x * dn; r.y = acc.y * dn; r.z = acc.z * dn; r.w = acc.w * dn;
    out[(size_t)node * LP + lane] = r;
}

// ---- fused pool + W3 + MLP head (one block per graph, sorted batch) ----

__global__ void poolhead_kernel(const float* __restrict__ h, const int* __restrict__ batch,
                                const float* __restrict__ W3, const float* __restrict__ b3,
                                const float* __restrict__ fw1, const float* __restrict__ fb1,
                                const float* __restrict__ fw2, const float* __restrict__ fb2,
                                float* __restrict__ out, int n) {
    int g = blockIdx.x;
    auto lb = [&](int key) {
        int lo = 0, hi = n;
        while (lo < hi) {
            int mid = (lo + hi) >> 1;
            if (batch[mid] < key) lo = mid + 1; else hi = mid;
        }
        return lo;
    };
    int lo = lb(g), hi = lb(g + 1);
    float c = (float)(hi - lo);
    float inv = (c > 0.0f) ? 1.0f / c : 0.0f;

    __shared__ float red[4][64];
    __shared__ float sp[64];
    __shared__ float p128[128];
    __shared__ float h64[64];

    int fo = threadIdx.x & 63;
    int sub = threadIdx.x >> 6;
    float acc = 0.0f;
    for (int i = lo + sub; i < hi; i += 4) acc += h[(size_t)i * 64 + fo];
    red[sub][fo] = acc;
    __syncthreads();
    if (sub == 0) sp[fo] = (red[0][fo] + red[1][fo] + red[2][fo] + red[3][fo]) * inv;
    __syncthreads();

    int j = threadIdx.x;
    if (j < 128) {
        float a = (c > 0.0f) ? b3[j] : 0.0f;  // empty graph: reference pooled128 = 0
#pragma unroll
        for (int k = 0; k < 64; ++k) a += sp[k] * W3[k * 128 + j];
        p128[j] = a;
    }
    __syncthreads();
    if (j < 64) {
        float a = fb1[j];
#pragma unroll
        for (int k = 0; k < 128; ++k) a += p128[k] * fw1[k * 64 + j];
        h64[j] = fmaxf(a, 0.0f);
    }
    __syncthreads();
    if (j < TGT) {
        float a = fb2[j];
#pragma unroll
        for (int k = 0; k < 64; ++k) a += h64[k] * fw2[k * TGT + j];
        out[(size_t)g * TGT + j] = a;
    }
}

extern "C" void kernel_launch(void* const* d_in, const int* in_sizes, int n_in,
                              void* d_out, int out_size, void* d_ws, size_t ws_size,
                              hipStream_t stream) {
    const float* x = (const float*)d_in[0];
    const int* edge_index = (const int*)d_in[1];
    const int* batch = (const int*)d_in[2];
    const float* W1 = (const float*)d_in[3];
    const float* b1 = (const float*)d_in[4];
    const float* W2 = (const float*)d_in[5];
    const float* b2 = (const float*)d_in[6];
    const float* W3 = (const float*)d_in[7];
    const float* b3 = (const float*)d_in[8];
    const float* fw1 = (const float*)d_in[9];
    const float* fb1 = (const float*)d_in[10];
    const float* fw2 = (const float*)d_in[11];
    const float* fb2 = (const float*)d_in[12];
    float* out = (float*)d_out;

    const int N = in_sizes[2];
    const int E = in_sizes[1] / 2;
    const int* src = edge_index;
    const int* dst = edge_index + E;

    // workspace layout: [incnt N][cursor N] contiguous for single memset
    int* incnt = (int*)d_ws;                     // N
    int* cursor = incnt + N;                     // N
    int* excl = cursor + N;                      // N
    int* psum = excl + N;                        // 256
    int* esrc = psum + 256;                      // E
    float* dis = (float*)(esrc + E);             // N
    float* bufA = dis + N;                       // N*64
    float* bufB = bufA + (size_t)N * 64;         // N*64

    const int T = 256;
    auto cdiv = [](long long a, long long b) { return (int)((a + b - 1) / b); };
    const int nb1 = cdiv(N, 256);

    // ---- CSR build ----
    hipMemsetAsync(incnt, 0, (size_t)2 * N * sizeof(int), stream);
    deg_count_kernel<<<cdiv(E, T), T, 0, stream>>>(dst, incnt, E);
    dis_scale_kernel<<<cdiv((long long)N * 16, T), T, 0, stream>>>(incnt, x, dis, bufA, N);
    scan1_kernel<<<nb1, 256, 0, stream>>>(incnt, excl, psum, N);
    scan2_kernel<<<1, 256, 0, stream>>>(psum, nb1);
    place_kernel<<<cdiv(E, T), T, 0, stream>>>(src, dst, excl, psum, cursor, esrc, E);

    // ---- layer 1: agg(16) + gemm 11->32 fused ----
    aggemm_kernel<16, 11, 32><<<cdiv(N, 64), T, 0, stream>>>(
        (const float4*)bufA, dis, excl, psum, incnt, esrc, W1, b1, bufB, N);

    // ---- layer 2: agg(32) + gemm 32->64 fused ----
    aggemm_kernel<32, 32, 64><<<cdiv(N, 32), T, 0, stream>>>(
        (const float4*)bufB, dis, excl, psum, incnt, esrc, W2, b2, bufA, N);

    // ---- layer 3: agg(64), then fused pool + W3 + MLP ----
    agg64_kernel<<<cdiv(N, 16), T, 0, stream>>>(
        (const float4*)bufA, dis, excl, psum, incnt, esrc, (float4*)bufB, N);
    poolhead_kernel<<<GG, 256, 0, stream>>>(bufB, batch, W3, b3, fw1, fb1, fw2, fb2, out, N);
}

// Round 6
// 166.022 us; speedup vs baseline: 5.0032x; 1.0257x over previous
//
#include <hip/hip_runtime.h>
#include <hip/hip_bf16.h>

// GCN: 3x GCNConv (11->32->64->128) + mean-pool + MLP (128->64->12)
// N=50000, E=600000, G=512.
// - aggregate-before-GEMM (agg widths 16(pad)/32/64), pool-before-GEMM for L3
// - on-device CSR; no cursor array (atomicSub on incnt), counts from scan diffs
// - custom zero kernel (hipMemsetAsync's fill was 44us for 400KB)

#define GG 512
#define TGT 12

// ---------------- zero N ints (int4 grid-stride) ----------------

__global__ void zero_kernel(int4* __restrict__ p, int n4) {
    int i = blockIdx.x * blockDim.x + threadIdx.x;
    if (i < n4) p[i] = make_int4(0, 0, 0, 0);
}

// ---------------- degree count ----------------

__global__ void deg_count_kernel(const int* __restrict__ dst, int* __restrict__ cnt, int E) {
    int i = blockIdx.x * blockDim.x + threadIdx.x;
    if (i < E) atomicAdd(&cnt[dst[i]], 1);
}

// ---------------- dis + padded/scaled x, fused ----------------

__global__ void dis_scale_kernel(const int* __restrict__ cnt, const float* __restrict__ x,
                                 float* __restrict__ dis, float* __restrict__ hs, int n) {
    long long idx = (long long)blockIdx.x * blockDim.x + threadIdx.x;
    int node = (int)(idx >> 4);
    int lane = (int)(idx & 15);
    if (node >= n) return;
    float d = rsqrtf(1.0f + (float)cnt[node]);
    if (lane == 0) dis[node] = d;
    hs[(size_t)node * 16 + lane] = (lane < 11) ? x[(size_t)node * 11 + lane] * d : 0.0f;
}

// ---------------- scan: block-exclusive + block sums, then scan of sums ----------------

__global__ void scan1_kernel(const int* __restrict__ cnt, int* __restrict__ excl,
                             int* __restrict__ psum, int n) {
    __shared__ int sh[256];
    int i = blockIdx.x * 256 + threadIdx.x;
    int v = (i < n) ? cnt[i] : 0;
    sh[threadIdx.x] = v;
    __syncthreads();
    for (int off = 1; off < 256; off <<= 1) {
        int t = (threadIdx.x >= (unsigned)off) ? sh[threadIdx.x - off] : 0;
        __syncthreads();
        sh[threadIdx.x] += t;
        __syncthreads();
    }
    if (i < n) excl[i] = sh[threadIdx.x] - v;  // exclusive within block
    if (threadIdx.x == 255) psum[blockIdx.x] = sh[255];
}

__global__ void scan2_kernel(int* __restrict__ psum, int nb) {
    __shared__ int sh[256];
    int carry = 0;
    for (int base = 0; base < nb; base += 256) {
        int i = base + threadIdx.x;
        int v = (i < nb) ? psum[i] : 0;
        sh[threadIdx.x] = v;
        __syncthreads();
        for (int off = 1; off < 256; off <<= 1) {
            int t = (threadIdx.x >= (unsigned)off) ? sh[threadIdx.x - off] : 0;
            __syncthreads();
            sh[threadIdx.x] += t;
            __syncthreads();
        }
        if (i < nb) psum[i] = sh[threadIdx.x] - v + carry;
        carry += sh[255];
        __syncthreads();
    }
}

// ---------------- edge placement into CSR (consumes incnt down to zero) ----------------

__global__ void place_kernel(const int* __restrict__ src, const int* __restrict__ dst,
                             const int* __restrict__ excl, const int* __restrict__ psum,
                             int* __restrict__ incnt, int* __restrict__ esrc, int E) {
    int i = blockIdx.x * blockDim.x + threadIdx.x;
    if (i < E) {
        int d = dst[i];
        int r = atomicSub(&incnt[d], 1) - 1;  // r in [0, cnt)
        int pos = excl[d] + psum[d >> 8] + r;
        esrc[pos] = src[i];
    }
}

__device__ __forceinline__ int offs_of(const int* __restrict__ excl,
                                       const int* __restrict__ psum, int i) {
    return excl[i] + psum[i >> 8];
}

// ---- fused agg + GEMM:  srow = dis[n]*(sum_in hs[s] + hs[n]);  out = relu(srow@W+b)*dis ----

template <int F, int FI, int FO>
__global__ void aggemm_kernel(const float4* __restrict__ hs, const float* __restrict__ dis,
                              const int* __restrict__ excl, const int* __restrict__ psum,
                              const int* __restrict__ esrc,
                              const float* __restrict__ W, const float* __restrict__ b,
                              float* __restrict__ out, int n, int Etot) {
    constexpr int LP = F / 4;       // float4 lanes per node
    constexpr int NPB = 256 / LP;   // nodes per block
    __shared__ float srow[NPB][F];
    __shared__ float sdn[NPB];
    __shared__ float sW[FI * FO];
    for (int i = threadIdx.x; i < FI * FO; i += 256) sW[i] = W[i];

    int nd = threadIdx.x / LP;
    int lane = threadIdx.x % LP;
    int node = blockIdx.x * NPB + nd;
    if (node < n) {
        float4 acc = hs[(size_t)node * LP + lane];
        int s0 = offs_of(excl, psum, node);
        int send = (node + 1 < n) ? offs_of(excl, psum, node + 1) : Etot;
        int c = send - s0;
        int e = 0;
        for (; e + 2 <= c; e += 2) {
            int sa = esrc[s0 + e], sb = esrc[s0 + e + 1];
            float4 va = hs[(size_t)sa * LP + lane];
            float4 vb = hs[(size_t)sb * LP + lane];
            acc.x += va.x + vb.x; acc.y += va.y + vb.y;
            acc.z += va.z + vb.z; acc.w += va.w + vb.w;
        }
        if (e < c) {
            int sa = esrc[s0 + e];
            float4 va = hs[(size_t)sa * LP + lane];
            acc.x += va.x; acc.y += va.y; acc.z += va.z; acc.w += va.w;
        }
        float dn = dis[node];
        srow[nd][lane * 4 + 0] = acc.x * dn;
        srow[nd][lane * 4 + 1] = acc.y * dn;
        srow[nd][lane * 4 + 2] = acc.z * dn;
        srow[nd][lane * 4 + 3] = acc.w * dn;
        if (lane == 0) sdn[nd] = dn;
    }
    __syncthreads();

    int base = blockIdx.x * NPB;
#pragma unroll
    for (int o = threadIdx.x; o < NPB * FO; o += 256) {
        int fo = o % FO;
        int nd2 = o / FO;
        int node2 = base + nd2;
        if (node2 < n) {
            float acc = b[fo];
#pragma unroll
            for (int fi = 0; fi < FI; ++fi) acc += srow[nd2][fi] * sW[fi * FO + fo];
            out[(size_t)node2 * FO + fo] = fmaxf(acc, 0.0f) * sdn[nd2];
        }
    }
}

// ---- layer-3 aggregation (width 64), standalone ----

__global__ void agg64_kernel(const float4* __restrict__ hs, const float* __restrict__ dis,
                             const int* __restrict__ excl, const int* __restrict__ psum,
                             const int* __restrict__ esrc, float4* __restrict__ out,
                             int n, int Etot) {
    constexpr int LP = 16;
    constexpr int NPB = 16;
    int node = blockIdx.x * NPB + (int)(threadIdx.x / LP);
    int lane = threadIdx.x % LP;
    if (node >= n) return;
    float4 acc = hs[(size_t)node * LP + lane];
    int s0 = offs_of(excl, psum, node);
    int send = (node + 1 < n) ? offs_of(excl, psum, node + 1) : Etot;
    int c = send - s0;
    int e = 0;
    for (; e + 2 <= c; e += 2) {
        int sa = esrc[s0 + e], sb = esrc[s0 + e + 1];
        float4 va = hs[(size_t)sa * LP + lane];
        float4 vb = hs[(size_t)sb * LP + lane];
        acc.x += va.x + vb.x; acc.y += va.y + vb.y;
        acc.z += va.z + vb.z; acc.w += va.w + vb.w;
    }
    if (e < c) {
        int sa = esrc[s0 + e];
        float4 va = hs[(size_t)sa * LP + lane];
        acc.x += va.x; acc.y += va.y; acc.z += va.z; acc.w += va.w;
    }
    float dn = dis[node];
    float4 r;
    r.x = acc.x * dn; r.y = acc.y * dn; r.z = acc.z * dn; r.w = acc.w * dn;
    out[(size_t)node * LP + lane] = r;
}

// ---- fused pool + W3 + MLP head (one block per graph, sorted batch) ----

__global__ void poolhead_kernel(const float* __restrict__ h, const int* __restrict__ batch,
                                const float* __restrict__ W3, const float* __restrict__ b3,
                                const float* __restrict__ fw1, const float* __restrict__ fb1,
                                const float* __restrict__ fw2, const float* __restrict__ fb2,
                                float* __restrict__ out, int n) {
    int g = blockIdx.x;
    auto lb = [&](int key) {
        int lo = 0, hi = n;
        while (lo < hi) {
            int mid = (lo + hi) >> 1;
            if (batch[mid] < key) lo = mid + 1; else hi = mid;
        }
        return lo;
    };
    int lo = lb(g), hi = lb(g + 1);
    float c = (float)(hi - lo);
    float inv = (c > 0.0f) ? 1.0f / c : 0.0f;

    __shared__ float red[4][64];
    __shared__ float sp[64];
    __shared__ float p128[128];
    __shared__ float h64[64];

    int fo = threadIdx.x & 63;
    int sub = threadIdx.x >> 6;
    float acc = 0.0f;
    for (int i = lo + sub; i < hi; i += 4) acc += h[(size_t)i * 64 + fo];
    red[sub][fo] = acc;
    __syncthreads();
    if (sub == 0) sp[fo] = (red[0][fo] + red[1][fo] + red[2][fo] + red[3][fo]) * inv;
    __syncthreads();

    int j = threadIdx.x;
    if (j < 128) {
        float a = (c > 0.0f) ? b3[j] : 0.0f;  // empty graph: reference pooled128 = 0
#pragma unroll
        for (int k = 0; k < 64; ++k) a += sp[k] * W3[k * 128 + j];
        p128[j] = a;
    }
    __syncthreads();
    if (j < 64) {
        float a = fb1[j];
#pragma unroll
        for (int k = 0; k < 128; ++k) a += p128[k] * fw1[k * 64 + j];
        h64[j] = fmaxf(a, 0.0f);
    }
    __syncthreads();
    if (j < TGT) {
        float a = fb2[j];
#pragma unroll
        for (int k = 0; k < 64; ++k) a += h64[k] * fw2[k * TGT + j];
        out[(size_t)g * TGT + j] = a;
    }
}

extern "C" void kernel_launch(void* const* d_in, const int* in_sizes, int n_in,
                              void* d_out, int out_size, void* d_ws, size_t ws_size,
                              hipStream_t stream) {
    const float* x = (const float*)d_in[0];
    const int* edge_index = (const int*)d_in[1];
    const int* batch = (const int*)d_in[2];
    const float* W1 = (const float*)d_in[3];
    const float* b1 = (const float*)d_in[4];
    const float* W2 = (const float*)d_in[5];
    const float* b2 = (const float*)d_in[6];
    const float* W3 = (const float*)d_in[7];
    const float* b3 = (const float*)d_in[8];
    const float* fw1 = (const float*)d_in[9];
    const float* fb1 = (const float*)d_in[10];
    const float* fw2 = (const float*)d_in[11];
    const float* fb2 = (const float*)d_in[12];
    float* out = (float*)d_out;

    const int N = in_sizes[2];
    const int E = in_sizes[1] / 2;
    const int* src = edge_index;
    const int* dst = edge_index + E;

    // workspace layout
    int* incnt = (int*)d_ws;                     // N (zeroed each call; consumed by place)
    int* excl = incnt + N;                       // N
    int* psum = excl + N;                        // 256
    int* esrc = psum + 256;                      // E
    float* dis = (float*)(esrc + E);             // N
    float* bufA = dis + N;                       // N*64
    float* bufB = bufA + (size_t)N * 64;         // N*64

    const int T = 256;
    auto cdiv = [](long long a, long long b) { return (int)((a + b - 1) / b); };
    const int nb1 = cdiv(N, 256);

    // ---- CSR build ----
    zero_kernel<<<cdiv(cdiv(N, 4), T), T, 0, stream>>>((int4*)incnt, cdiv(N, 4));
    deg_count_kernel<<<cdiv(E, T), T, 0, stream>>>(dst, incnt, E);
    dis_scale_kernel<<<cdiv((long long)N * 16, T), T, 0, stream>>>(incnt, x, dis, bufA, N);
    scan1_kernel<<<nb1, 256, 0, stream>>>(incnt, excl, psum, N);
    scan2_kernel<<<1, 256, 0, stream>>>(psum, nb1);
    place_kernel<<<cdiv(E, T), T, 0, stream>>>(src, dst, excl, psum, incnt, esrc, E);

    // ---- layer 1: agg(16) + gemm 11->32 fused ----
    aggemm_kernel<16, 11, 32><<<cdiv(N, 64), T, 0, stream>>>(
        (const float4*)bufA, dis, excl, psum, esrc, W1, b1, bufB, N, E);

    // ---- layer 2: agg(32) + gemm 32->64 fused ----
    aggemm_kernel<32, 32, 64><<<cdiv(N, 32), T, 0, stream>>>(
        (const float4*)bufB, dis, excl, psum, esrc, W2, b2, bufA, N, E);

    // ---- layer 3: agg(64), then fused pool + W3 + MLP ----
    agg64_kernel<<<cdiv(N, 16), T, 0, stream>>>(
        (const float4*)bufA, dis, excl, psum, esrc, (float4*)bufB, N, E);
    poolhead_kernel<<<GG, 256, 0, stream>>>(bufB, batch, W3, b3, fw1, fb1, fw2, fb2, out, N);
}

// Round 7
// 148.161 us; speedup vs baseline: 5.6064x; 1.1206x over previous
//
#include <hip/hip_runtime.h>
#include <hip/hip_bf16.h>
#include <hip/hip_fp16.h>

// GCN: 3x GCNConv (11->32->64->128) + mean-pool + MLP (128->64->12)
// N=50000, E=600000, G=512.
// - aggregate-before-GEMM (agg widths 16(pad)/32/64), pool-before-GEMM for L3
// - on-device CSR; counts from scan diffs; atomicSub claims slots
// - fp16 storage for h1/h2/h3 intermediates -> halves gather bytes/edge

#define GG 512
#define TGT 12

union F4H8 { float4 f4; __half2 h2[4]; };

__device__ __forceinline__ void acc_add_h8(float* acc, float4 raw) {
    F4H8 u; u.f4 = raw;
#pragma unroll
    for (int k = 0; k < 4; ++k) {
        float2 f = __half22float2(u.h2[k]);
        acc[2 * k] += f.x;
        acc[2 * k + 1] += f.y;
    }
}

// ---------------- zero N ints (int4 grid-stride) ----------------

__global__ void zero_kernel(int4* __restrict__ p, int n4) {
    int i = blockIdx.x * blockDim.x + threadIdx.x;
    if (i < n4) p[i] = make_int4(0, 0, 0, 0);
}

// ---------------- degree count ----------------

__global__ void deg_count_kernel(const int* __restrict__ dst, int* __restrict__ cnt, int E) {
    int i = blockIdx.x * blockDim.x + threadIdx.x;
    if (i < E) atomicAdd(&cnt[dst[i]], 1);
}

// ---------------- dis + padded/scaled x (f32), fused ----------------

__global__ void dis_scale_kernel(const int* __restrict__ cnt, const float* __restrict__ x,
                                 float* __restrict__ dis, float* __restrict__ hs, int n) {
    long long idx = (long long)blockIdx.x * blockDim.x + threadIdx.x;
    int node = (int)(idx >> 4);
    int lane = (int)(idx & 15);
    if (node >= n) return;
    float d = rsqrtf(1.0f + (float)cnt[node]);
    if (lane == 0) dis[node] = d;
    hs[(size_t)node * 16 + lane] = (lane < 11) ? x[(size_t)node * 11 + lane] * d : 0.0f;
}

// ---------------- scan ----------------

__global__ void scan1_kernel(const int* __restrict__ cnt, int* __restrict__ excl,
                             int* __restrict__ psum, int n) {
    __shared__ int sh[256];
    int i = blockIdx.x * 256 + threadIdx.x;
    int v = (i < n) ? cnt[i] : 0;
    sh[threadIdx.x] = v;
    __syncthreads();
    for (int off = 1; off < 256; off <<= 1) {
        int t = (threadIdx.x >= (unsigned)off) ? sh[threadIdx.x - off] : 0;
        __syncthreads();
        sh[threadIdx.x] += t;
        __syncthreads();
    }
    if (i < n) excl[i] = sh[threadIdx.x] - v;
    if (threadIdx.x == 255) psum[blockIdx.x] = sh[255];
}

__global__ void scan2_kernel(int* __restrict__ psum, int nb) {
    __shared__ int sh[256];
    int carry = 0;
    for (int base = 0; base < nb; base += 256) {
        int i = base + threadIdx.x;
        int v = (i < nb) ? psum[i] : 0;
        sh[threadIdx.x] = v;
        __syncthreads();
        for (int off = 1; off < 256; off <<= 1) {
            int t = (threadIdx.x >= (unsigned)off) ? sh[threadIdx.x - off] : 0;
            __syncthreads();
            sh[threadIdx.x] += t;
            __syncthreads();
        }
        if (i < nb) psum[i] = sh[threadIdx.x] - v + carry;
        carry += sh[255];
        __syncthreads();
    }
}

// ---------------- edge placement into CSR (consumes incnt down to zero) ----------------

__global__ void place_kernel(const int* __restrict__ src, const int* __restrict__ dst,
                             const int* __restrict__ excl, const int* __restrict__ psum,
                             int* __restrict__ incnt, int* __restrict__ esrc, int E) {
    int i = blockIdx.x * blockDim.x + threadIdx.x;
    if (i < E) {
        int d = dst[i];
        int r = atomicSub(&incnt[d], 1) - 1;
        int pos = excl[d] + psum[d >> 8] + r;
        esrc[pos] = src[i];
    }
}

__device__ __forceinline__ int offs_of(const int* __restrict__ excl,
                                       const int* __restrict__ psum, int i) {
    return excl[i] + psum[i >> 8];
}

// ---- layer 1: f32 gather (width 16) + GEMM 11->32, half output ----

template <int F, int FI, int FO>
__global__ void aggemm_f32_kernel(const float4* __restrict__ hs, const float* __restrict__ dis,
                                  const int* __restrict__ excl, const int* __restrict__ psum,
                                  const int* __restrict__ esrc,
                                  const float* __restrict__ W, const float* __restrict__ b,
                                  __half* __restrict__ out, int n, int Etot) {
    constexpr int LP = F / 4;
    constexpr int NPB = 256 / LP;
    __shared__ float srow[NPB][F];
    __shared__ float sdn[NPB];
    __shared__ float sW[FI * FO];
    for (int i = threadIdx.x; i < FI * FO; i += 256) sW[i] = W[i];

    int nd = threadIdx.x / LP;
    int lane = threadIdx.x % LP;
    int node = blockIdx.x * NPB + nd;
    if (node < n) {
        float4 acc = hs[(size_t)node * LP + lane];
        int s0 = offs_of(excl, psum, node);
        int send = (node + 1 < n) ? offs_of(excl, psum, node + 1) : Etot;
        int c = send - s0;
        int e = 0;
        for (; e + 2 <= c; e += 2) {
            int sa = esrc[s0 + e], sb = esrc[s0 + e + 1];
            float4 va = hs[(size_t)sa * LP + lane];
            float4 vb = hs[(size_t)sb * LP + lane];
            acc.x += va.x + vb.x; acc.y += va.y + vb.y;
            acc.z += va.z + vb.z; acc.w += va.w + vb.w;
        }
        if (e < c) {
            int sa = esrc[s0 + e];
            float4 va = hs[(size_t)sa * LP + lane];
            acc.x += va.x; acc.y += va.y; acc.z += va.z; acc.w += va.w;
        }
        float dn = dis[node];
        srow[nd][lane * 4 + 0] = acc.x * dn;
        srow[nd][lane * 4 + 1] = acc.y * dn;
        srow[nd][lane * 4 + 2] = acc.z * dn;
        srow[nd][lane * 4 + 3] = acc.w * dn;
        if (lane == 0) sdn[nd] = dn;
    }
    __syncthreads();

    int base = blockIdx.x * NPB;
    for (int o = threadIdx.x; o < NPB * FO; o += 256) {
        int fo = o % FO;
        int nd2 = o / FO;
        int node2 = base + nd2;
        if (node2 < n) {
            float acc = b[fo];
#pragma unroll
            for (int fi = 0; fi < FI; ++fi) acc += srow[nd2][fi] * sW[fi * FO + fo];
            out[(size_t)node2 * FO + fo] = __float2half(fmaxf(acc, 0.0f) * sdn[nd2]);
        }
    }
}

// ---- layer 2: fp16 gather (width F halves) + GEMM FI->FO, half output ----

template <int F, int FI, int FO>
__global__ void aggemm_h_kernel(const float4* __restrict__ hs, const float* __restrict__ dis,
                                const int* __restrict__ excl, const int* __restrict__ psum,
                                const int* __restrict__ esrc,
                                const float* __restrict__ W, const float* __restrict__ b,
                                __half* __restrict__ out, int n, int Etot) {
    constexpr int LP = F / 8;       // float4 = 8 halves
    constexpr int NPB = 256 / LP;
    __shared__ float srow[NPB][F];
    __shared__ float sdn[NPB];
    __shared__ float sW[FI * FO];
    for (int i = threadIdx.x; i < FI * FO; i += 256) sW[i] = W[i];

    int nd = threadIdx.x / LP;
    int lane = threadIdx.x % LP;
    int node = blockIdx.x * NPB + nd;
    if (node < n) {
        float acc[8] = {0, 0, 0, 0, 0, 0, 0, 0};
        acc_add_h8(acc, hs[(size_t)node * LP + lane]);  // self
        int s0 = offs_of(excl, psum, node);
        int send = (node + 1 < n) ? offs_of(excl, psum, node + 1) : Etot;
        int c = send - s0;
        int e = 0;
        for (; e + 2 <= c; e += 2) {
            int sa = esrc[s0 + e], sb = esrc[s0 + e + 1];
            float4 va = hs[(size_t)sa * LP + lane];
            float4 vb = hs[(size_t)sb * LP + lane];
            acc_add_h8(acc, va);
            acc_add_h8(acc, vb);
        }
        if (e < c) acc_add_h8(acc, hs[(size_t)esrc[s0 + e] * LP + lane]);
        float dn = dis[node];
#pragma unroll
        for (int j = 0; j < 8; ++j) srow[nd][lane * 8 + j] = acc[j] * dn;
        if (lane == 0) sdn[nd] = dn;
    }
    __syncthreads();

    int base = blockIdx.x * NPB;
    for (int o = threadIdx.x; o < NPB * FO; o += 256) {
        int fo = o % FO;
        int nd2 = o / FO;
        int node2 = base + nd2;
        if (node2 < n) {
            float acc = b[fo];
#pragma unroll
            for (int fi = 0; fi < FI; ++fi) acc += srow[nd2][fi] * sW[fi * FO + fo];
            out[(size_t)node2 * FO + fo] = __float2half(fmaxf(acc, 0.0f) * sdn[nd2]);
        }
    }
}

// ---- layer 3: fp16 gather (width 64 halves), packed half output ----

__global__ void agg64h_kernel(const float4* __restrict__ hs, const float* __restrict__ dis,
                              const int* __restrict__ excl, const int* __restrict__ psum,
                              const int* __restrict__ esrc, float4* __restrict__ out,
                              int n, int Etot) {
    constexpr int LP = 8;    // 64 halves per row / 8 halves per float4
    constexpr int NPB = 32;
    int node = blockIdx.x * NPB + (int)(threadIdx.x / LP);
    int lane = threadIdx.x % LP;
    if (node >= n) return;
    float acc[8] = {0, 0, 0, 0, 0, 0, 0, 0};
    acc_add_h8(acc, hs[(size_t)node * LP + lane]);  // self
    int s0 = offs_of(excl, psum, node);
    int send = (node + 1 < n) ? offs_of(excl, psum, node + 1) : Etot;
    int c = send - s0;
    int e = 0;
    for (; e + 2 <= c; e += 2) {
        int sa = esrc[s0 + e], sb = esrc[s0 + e + 1];
        float4 va = hs[(size_t)sa * LP + lane];
        float4 vb = hs[(size_t)sb * LP + lane];
        acc_add_h8(acc, va);
        acc_add_h8(acc, vb);
    }
    if (e < c) acc_add_h8(acc, hs[(size_t)esrc[s0 + e] * LP + lane]);
    float dn = dis[node];
    F4H8 w;
#pragma unroll
    for (int k = 0; k < 4; ++k)
        w.h2[k] = __float22half2_rn(make_float2(acc[2 * k] * dn, acc[2 * k + 1] * dn));
    out[(size_t)node * LP + lane] = w.f4;
}

// ---- fused pool + W3 + MLP head (one block per graph, sorted batch) ----

__global__ void poolhead_kernel(const __half* __restrict__ h, const int* __restrict__ batch,
                                const float* __restrict__ W3, const float* __restrict__ b3,
                                const float* __restrict__ fw1, const float* __restrict__ fb1,
                                const float* __restrict__ fw2, const float* __restrict__ fb2,
                                float* __restrict__ out, int n) {
    int g = blockIdx.x;
    auto lb = [&](int key) {
        int lo = 0, hi = n;
        while (lo < hi) {
            int mid = (lo + hi) >> 1;
            if (batch[mid] < key) lo = mid + 1; else hi = mid;
        }
        return lo;
    };
    int lo = lb(g), hi = lb(g + 1);
    float c = (float)(hi - lo);
    float inv = (c > 0.0f) ? 1.0f / c : 0.0f;

    __shared__ float red[4][64];
    __shared__ float sp[64];
    __shared__ float p128[128];
    __shared__ float h64[64];

    int fo = threadIdx.x & 63;
    int sub = threadIdx.x >> 6;
    float acc = 0.0f;
    for (int i = lo + sub; i < hi; i += 4) acc += __half2float(h[(size_t)i * 64 + fo]);
    red[sub][fo] = acc;
    __syncthreads();
    if (sub == 0) sp[fo] = (red[0][fo] + red[1][fo] + red[2][fo] + red[3][fo]) * inv;
    __syncthreads();

    int j = threadIdx.x;
    if (j < 128) {
        float a = (c > 0.0f) ? b3[j] : 0.0f;  // empty graph: reference pooled128 = 0
#pragma unroll
        for (int k = 0; k < 64; ++k) a += sp[k] * W3[k * 128 + j];
        p128[j] = a;
    }
    __syncthreads();
    if (j < 64) {
        float a = fb1[j];
#pragma unroll
        for (int k = 0; k < 128; ++k) a += p128[k] * fw1[k * 64 + j];
        h64[j] = fmaxf(a, 0.0f);
    }
    __syncthreads();
    if (j < TGT) {
        float a = fb2[j];
#pragma unroll
        for (int k = 0; k < 64; ++k) a += h64[k] * fw2[k * TGT + j];
        out[(size_t)g * TGT + j] = a;
    }
}

extern "C" void kernel_launch(void* const* d_in, const int* in_sizes, int n_in,
                              void* d_out, int out_size, void* d_ws, size_t ws_size,
                              hipStream_t stream) {
    const float* x = (const float*)d_in[0];
    const int* edge_index = (const int*)d_in[1];
    const int* batch = (const int*)d_in[2];
    const float* W1 = (const float*)d_in[3];
    const float* b1 = (const float*)d_in[4];
    const float* W2 = (const float*)d_in[5];
    const float* b2 = (const float*)d_in[6];
    const float* W3 = (const float*)d_in[7];
    const float* b3 = (const float*)d_in[8];
    const float* fw1 = (const float*)d_in[9];
    const float* fb1 = (const float*)d_in[10];
    const float* fw2 = (const float*)d_in[11];
    const float* fb2 = (const float*)d_in[12];
    float* out = (float*)d_out;

    const int N = in_sizes[2];
    const int E = in_sizes[1] / 2;
    const int* src = edge_index;
    const int* dst = edge_index + E;

    // workspace layout (all chunk sizes are multiples of 16B)
    int* incnt = (int*)d_ws;                     // N
    int* excl = incnt + N;                       // N
    int* psum = excl + N;                        // 256
    int* esrc = psum + 256;                      // E
    float* dis = (float*)(esrc + E);             // N f32
    float* hx = dis + N;                         // N*16 f32
    __half* h1 = (__half*)(hx + (size_t)N * 16); // N*32 half
    __half* h2 = h1 + (size_t)N * 32;            // N*64 half
    __half* h3 = h2 + (size_t)N * 64;            // N*64 half

    const int T = 256;
    auto cdiv = [](long long a, long long b) { return (int)((a + b - 1) / b); };
    const int nb1 = cdiv(N, 256);

    // ---- CSR build ----
    zero_kernel<<<cdiv(cdiv(N, 4), T), T, 0, stream>>>((int4*)incnt, cdiv(N, 4));
    deg_count_kernel<<<cdiv(E, T), T, 0, stream>>>(dst, incnt, E);
    dis_scale_kernel<<<cdiv((long long)N * 16, T), T, 0, stream>>>(incnt, x, dis, hx, N);
    scan1_kernel<<<nb1, 256, 0, stream>>>(incnt, excl, psum, N);
    scan2_kernel<<<1, 256, 0, stream>>>(psum, nb1);
    place_kernel<<<cdiv(E, T), T, 0, stream>>>(src, dst, excl, psum, incnt, esrc, E);

    // ---- layer 1: f32 agg(16) + gemm 11->32, half out ----
    aggemm_f32_kernel<16, 11, 32><<<cdiv(N, 64), T, 0, stream>>>(
        (const float4*)hx, dis, excl, psum, esrc, W1, b1, h1, N, E);

    // ---- layer 2: fp16 agg(32) + gemm 32->64, half out ----
    aggemm_h_kernel<32, 32, 64><<<cdiv(N, 64), T, 0, stream>>>(
        (const float4*)h1, dis, excl, psum, esrc, W2, b2, h2, N, E);

    // ---- layer 3: fp16 agg(64), then fused pool + W3 + MLP ----
    agg64h_kernel<<<cdiv(N, 32), T, 0, stream>>>(
        (const float4*)h2, dis, excl, psum, esrc, (float4*)h3, N, E);
    poolhead_kernel<<<GG, 256, 0, stream>>>(h3, batch, W3, b3, fw1, fb1, fw2, fb2, out, N);
}